// Round 2
// baseline (704.711 us; speedup 1.0000x reference)
//
#include <hip/hip_runtime.h>
#include <math.h>

#define DIM 64
#define KC 32
#define NPTS 32768
#define LOG_2PI 1.8378770664093453f

// ============================================================================
// Prep: one block (256 threads = 4 waves) per component k.
//   Sigma = tril(L) tril(L)^T + I  -> Cholesky C -> M = C^{-1} (lower),
//   q = M mu, const_k = -0.5*(D*log2pi + logdet) + log_softmax(w)_k
// All hot loops have static bounds (pipelineable); Cholesky trailing update
// is wave-parallel over rows with lane = column.
// ============================================================================
__global__ __launch_bounds__(256) void prep_kernel(
    const float* __restrict__ L, const float* __restrict__ mu,
    const float* __restrict__ w, float* __restrict__ Mout,
    float* __restrict__ qout, float* __restrict__ cout)
{
    const int k = blockIdx.x;
    const int t = threadIdx.x;      // 0..255
    const int wv = t >> 6;          // 0..3
    const int lane = t & 63;
    __shared__ float Ls[DIM][DIM + 1];   // tril(L); later M
    __shared__ float Cc[DIM][DIM + 1];   // Sigma -> C (lower)
    __shared__ float logdet_s;

    // load tril(L), zeros above diag (makes Sigma loop bounds static)
    for (int idx = t; idx < DIM * DIM; idx += 256) {
        int r = idx >> 6, c = idx & 63;
        float v = L[k * DIM * DIM + idx];
        Ls[r][c] = (c <= r) ? v : 0.f;
    }
    __syncthreads();

    // Sigma[i][j] = sum_l Ls[i][l]*Ls[j][l] + (i==j). Static 64-bound l-loop
    // (upper-tril zeros make it equal to the triangular sum). wave -> 16 rows.
    for (int ii = 0; ii < 16; ++ii) {
        const int i = wv * 16 + ii;
        float s0 = 0.f, s1 = 0.f;
#pragma unroll
        for (int l = 0; l < DIM; l += 2) {
            s0 = fmaf(Ls[i][l], Ls[lane][l], s0);
            s1 = fmaf(Ls[i][l + 1], Ls[lane][l + 1], s1);
        }
        float s = s0 + s1;
        if (i == lane) s += 1.f;
        Cc[i][lane] = s;
    }
    __syncthreads();

    // Right-looking Cholesky, lower triangle in place.
    for (int c = 0; c < DIM; ++c) {
        if (wv == 0) {
            // wave-synchronous: all lanes read before lane c writes
            float pc = Cc[c][c];
            float dd = sqrtf(pc);
            float v = Cc[lane][c];
            Cc[lane][c] = (lane == c) ? dd : ((lane > c) ? v / dd : 0.f);
        }
        __syncthreads();
        for (int r = c + 1 + wv; r < DIM; r += 4) {
            float lrc = Cc[r][c];
            if (lane > c && lane <= r)
                Cc[r][lane] -= lrc * Cc[lane][c];
        }
        __syncthreads();
    }

    // logdet = 2*sum(log(diag C)) via wave 0 shuffle reduce
    if (wv == 0) {
        float dl = logf(Cc[lane][lane]);
#pragma unroll
        for (int off = 32; off > 0; off >>= 1)
            dl += __shfl_xor(dl, off, 64);
        if (lane == 0) logdet_s = 2.f * dl;
    }

    // M = C^{-1}: per-lane forward substitution, lane = column. y in regs,
    // static bounds after full unroll; y[l]=0 for l<lane keeps it exact.
    if (wv == 0) {
        float y[DIM];
#pragma unroll
        for (int i = 0; i < DIM; ++i) {
            float s0 = (i == lane) ? 1.f : 0.f, s1 = 0.f;
#pragma unroll
            for (int l = 0; l + 1 < i; l += 2) {
                s0 = fmaf(-Cc[i][l], y[l], s0);
                s1 = fmaf(-Cc[i][l + 1], y[l + 1], s1);
            }
            if (i & 1) s0 = fmaf(-Cc[i][i - 1], y[i - 1], s0);
            float val = (s0 + s1) / Cc[i][i];
            y[i] = (i >= lane) ? val : 0.f;
            Ls[i][lane] = y[i];
        }
    }
    __syncthreads();

    // write M dense (coalesced, all 4 waves)
    for (int idx = t; idx < DIM * DIM; idx += 256)
        Mout[k * DIM * DIM + idx] = Ls[idx >> 6][idx & 63];

    if (wv == 0) {
        // q_i = sum_{j<=i} M[i][j] * mu[j]
        float s = 0.f;
        for (int j = 0; j <= lane; ++j)
            s = fmaf(Ls[lane][j], mu[k * DIM + j], s);
        qout[k * DIM + lane] = s;
    }
    if (t == 0) {
        float wm = -3.0e38f;
        for (int i = 0; i < KC; ++i) wm = fmaxf(wm, w[i]);
        float se = 0.f;
        for (int i = 0; i < KC; ++i) se += __expf(w[i] - wm);
        float logw = w[k] - (wm + logf(se));
        cout[k] = -0.5f * (DIM * LOG_2PI + logdet_s) + logw;
    }
}

// ============================================================================
// Main: final scalar is logsumexp over the FLAT (n,k) set, so each wave
// independently owns 64 rows x 2 components; no per-row merge needed.
// 2048 blocks x 256 threads = 8192 waves. x pinned in VGPRs; M/q/cst are
// wave-uniform -> s_load + v_fmac with SGPR operand.
// ============================================================================
__global__ __launch_bounds__(256, 5) void main_kernel(
    const float* __restrict__ X, const float* __restrict__ M,
    const float* __restrict__ q, const float* __restrict__ cst,
    float2* __restrict__ partials)
{
    const int tid = threadIdx.x;
    const int lane = tid & 63;
    const int wv = tid >> 6;                 // 0..3
    const int wid = blockIdx.x * 4 + wv;     // 0..8191
    const int g = wid >> 4;                  // row-group 0..511
    const int s = __builtin_amdgcn_readfirstlane(wid & 15);  // k-subset
    const int n = g * 64 + lane;

    float x[DIM];
    const float4* X4 = (const float4*)X + n * (DIM / 4);
#pragma unroll
    for (int j4 = 0; j4 < DIM / 4; ++j4) {
        float4 v = X4[j4];
        x[4 * j4 + 0] = v.x; x[4 * j4 + 1] = v.y;
        x[4 * j4 + 2] = v.z; x[4 * j4 + 3] = v.w;
    }
#pragma unroll
    for (int j = 0; j < DIM; ++j) asm volatile("" : "+v"(x[j]));

    float m_r = -3.0e38f, s_r = 0.f;
#pragma unroll 1
    for (int kk = 0; kk < 2; ++kk) {
        const int k = s + kk * 16;           // uniform
        const float* __restrict__ Mk = M + k * DIM * DIM;
        const float* __restrict__ qk = q + k * DIM;
        float mh0 = 0.f, mh1 = 0.f, mh2 = 0.f, mh3 = 0.f;
#pragma unroll
        for (int ib = 0; ib < 4; ++ib) {
            const int JMAX = (ib + 1) * 16;  // constant after unroll
#pragma unroll
            for (int i2 = 0; i2 < 16; ++i2) {
                const int i = ib * 16 + i2;
                float y = -qk[i];
#pragma unroll
                for (int j = 0; j < JMAX; ++j)
                    y = fmaf(Mk[i * DIM + j], x[j], y);
                if ((i2 & 3) == 0)      mh0 = fmaf(y, y, mh0);
                else if ((i2 & 3) == 1) mh1 = fmaf(y, y, mh1);
                else if ((i2 & 3) == 2) mh2 = fmaf(y, y, mh2);
                else                    mh3 = fmaf(y, y, mh3);
            }
        }
        float maha = (mh0 + mh1) + (mh2 + mh3);
        float logp = fmaf(-0.5f, maha, cst[k]);
        float mn = fmaxf(m_r, logp);
        s_r = s_r * __expf(m_r - mn) + __expf(logp - mn);
        m_r = mn;
    }

    // merge 64 lanes' (m,s) pairs (flat logsumexp partials)
#pragma unroll
    for (int off = 32; off > 0; off >>= 1) {
        float om = __shfl_xor(m_r, off, 64);
        float os = __shfl_xor(s_r, off, 64);
        float mn = fmaxf(m_r, om);
        s_r = s_r * __expf(m_r - mn) + os * __expf(om - mn);
        m_r = mn;
    }
    __shared__ float2 pm[4];
    if (lane == 0) pm[wv] = make_float2(m_r, s_r);
    __syncthreads();
    if (tid == 0) {
        float mm = pm[0].x, ss = pm[0].y;
#pragma unroll
        for (int i = 1; i < 4; ++i) {
            float mn = fmaxf(mm, pm[i].x);
            ss = ss * __expf(mm - mn) + pm[i].y * __expf(pm[i].x - mn);
            mm = mn;
        }
        partials[blockIdx.x] = make_float2(mm, ss);
    }
}

// ============================================================================
// Final: merge 2048 block partials -> scalar
// ============================================================================
__global__ __launch_bounds__(256) void final_kernel(
    const float2* __restrict__ partials, int nparts, float* __restrict__ out)
{
    const int tid = threadIdx.x;
    const int lane = tid & 63;
    const int wv = tid >> 6;
    float mm = -3.0e38f, ss = 0.f;
    for (int i = tid; i < nparts; i += 256) {
        float2 p = partials[i];
        float mn = fmaxf(mm, p.x);
        ss = ss * __expf(mm - mn) + p.y * __expf(p.x - mn);
        mm = mn;
    }
#pragma unroll
    for (int off = 32; off > 0; off >>= 1) {
        float om = __shfl_xor(mm, off, 64);
        float os = __shfl_xor(ss, off, 64);
        float mn = fmaxf(mm, om);
        ss = ss * __expf(mm - mn) + os * __expf(om - mn);
        mm = mn;
    }
    __shared__ float2 pm[4];
    if (lane == 0) pm[wv] = make_float2(mm, ss);
    __syncthreads();
    if (tid == 0) {
        float m2 = pm[0].x, s2 = pm[0].y;
#pragma unroll
        for (int i = 1; i < 4; ++i) {
            float mn = fmaxf(m2, pm[i].x);
            s2 = s2 * __expf(m2 - mn) + pm[i].y * __expf(pm[i].x - mn);
            m2 = mn;
        }
        out[0] = -(m2 + logf(s2));
    }
}

extern "C" void kernel_launch(void* const* d_in, const int* in_sizes, int n_in,
                              void* d_out, int out_size, void* d_ws, size_t ws_size,
                              hipStream_t stream) {
    const float* X  = (const float*)d_in[0];   // [32768,64]
    const float* mu = (const float*)d_in[1];   // [32,64]
    const float* L  = (const float*)d_in[2];   // [32,64,64]
    const float* w  = (const float*)d_in[3];   // [32]
    // d_in[4] = it (unused)

    float* ws   = (float*)d_ws;
    float* Mbuf = ws;                       // 32*4096 floats
    float* qbuf = Mbuf + KC * DIM * DIM;    // 32*64
    float* cbuf = qbuf + KC * DIM;          // 32
    float2* parts = (float2*)(cbuf + KC);   // 2048 float2 (8-byte aligned)

    prep_kernel<<<KC, 256, 0, stream>>>(L, mu, w, Mbuf, qbuf, cbuf);
    main_kernel<<<2048, 256, 0, stream>>>(X, Mbuf, qbuf, cbuf, parts);
    final_kernel<<<1, 256, 0, stream>>>(parts, 2048, (float*)d_out);
}

// Round 3
// 199.346 us; speedup vs baseline: 3.5351x; 3.5351x over previous
//
#include <hip/hip_runtime.h>
#include <math.h>

#define DIM 64
#define KC 32
#define NPTS 32768
#define LOG_2PI 1.8378770664093453f
#define C0 (-58.0f)   // fixed logsumexp reference: logp <= -58.81 always (logdet>=0, logw<=0)

typedef __attribute__((ext_vector_type(8))) short short8;
typedef __attribute__((ext_vector_type(4))) float float4v;

__device__ __forceinline__ unsigned short f2bf(float f) {
    unsigned u = __float_as_uint(f);
    u += 0x7FFFu + ((u >> 16) & 1u);   // RNE
    return (unsigned short)(u >> 16);
}

// ============================================================================
// Prep: one block (256 threads) per component k.
//   Sigma = tril(L)tril(L)^T + I -> Cholesky C -> M = C^{-1} -> q = M mu.
// Outputs:
//   Bpack[k]: 12 MFMA B-fragments (4 col-tiles x 3 k-tiles) in exact
//             B-operand layout: element e of lane ln holds
//             B[kdim=(kt*32 + (ln>>4)*8 + e)][col=ct*16+(ln&15)], where
//             B[j][i] = M[i][j] for j<64 and row 64 = -q (augmented K-tile
//             that folds the q-subtraction into the GEMM; rows 65.. = 0).
//   cstC[k] = -0.5*(D*log2pi + logdet) + log_softmax(w)_k - C0
// ============================================================================
__global__ __launch_bounds__(256) void prep_kernel(
    const float* __restrict__ L, const float* __restrict__ mu,
    const float* __restrict__ w, short* __restrict__ Bpack,
    float* __restrict__ cstC)
{
    const int k = blockIdx.x;
    const int t = threadIdx.x;      // 0..255
    const int wv = t >> 6;          // 0..3
    const int lane = t & 63;
    __shared__ float Ls[DIM][DIM + 1];   // tril(L); later M
    __shared__ float Cc[DIM][DIM + 1];   // Sigma -> C (lower)
    __shared__ float qs[DIM];
    __shared__ float logdet_s;

    // load tril(L), zeros above diag
    for (int idx = t; idx < DIM * DIM; idx += 256) {
        int r = idx >> 6, c = idx & 63;
        float v = L[k * DIM * DIM + idx];
        Ls[r][c] = (c <= r) ? v : 0.f;
    }
    __syncthreads();

    // Sigma[i][j] = sum_l Ls[i][l]*Ls[j][l] + (i==j); static 64-bound l-loop.
    for (int ii = 0; ii < 16; ++ii) {
        const int i = wv * 16 + ii;
        float s0 = 0.f, s1 = 0.f;
#pragma unroll
        for (int l = 0; l < DIM; l += 2) {
            s0 = fmaf(Ls[i][l], Ls[lane][l], s0);
            s1 = fmaf(Ls[i][l + 1], Ls[lane][l + 1], s1);
        }
        float s = s0 + s1;
        if (i == lane) s += 1.f;
        Cc[i][lane] = s;
    }
    __syncthreads();

    // Right-looking Cholesky, lower triangle in place. (verified round 2)
    for (int c = 0; c < DIM; ++c) {
        if (wv == 0) {
            float pc = Cc[c][c];
            float dd = sqrtf(pc);
            float v = Cc[lane][c];
            Cc[lane][c] = (lane == c) ? dd : ((lane > c) ? v / dd : 0.f);
        }
        __syncthreads();
        for (int r = c + 1 + wv; r < DIM; r += 4) {
            float lrc = Cc[r][c];
            if (lane > c && lane <= r)
                Cc[r][lane] -= lrc * Cc[lane][c];
        }
        __syncthreads();
    }

    if (wv == 0) {
        float dl = logf(Cc[lane][lane]);
#pragma unroll
        for (int off = 32; off > 0; off >>= 1)
            dl += __shfl_xor(dl, off, 64);
        if (lane == 0) logdet_s = 2.f * dl;
    }

    // M = C^{-1}: per-lane forward substitution, lane = column. (verified r2)
    if (wv == 0) {
        float y[DIM];
#pragma unroll
        for (int i = 0; i < DIM; ++i) {
            float s0 = (i == lane) ? 1.f : 0.f, s1 = 0.f;
#pragma unroll
            for (int l = 0; l + 1 < i; l += 2) {
                s0 = fmaf(-Cc[i][l], y[l], s0);
                s1 = fmaf(-Cc[i][l + 1], y[l + 1], s1);
            }
            if (i & 1) s0 = fmaf(-Cc[i][i - 1], y[i - 1], s0);
            float val = (s0 + s1) / Cc[i][i];
            y[i] = (i >= lane) ? val : 0.f;
            Ls[i][lane] = y[i];
        }
        // q_i = sum_{j<=i} M[i][j]*mu[j]  (same wave: Ls writes are visible)
        float s = 0.f;
        for (int j = 0; j <= lane; ++j)
            s = fmaf(Ls[lane][j], mu[k * DIM + j], s);
        qs[lane] = s;
    }
    if (t == 0) {
        float wm = -3.0e38f;
        for (int i = 0; i < KC; ++i) wm = fmaxf(wm, w[i]);
        float se = 0.f;
        for (int i = 0; i < KC; ++i) se += __expf(w[i] - wm);
        float logw = w[k] - (wm + logf(se));
        cstC[k] = -0.5f * (DIM * LOG_2PI + logdet_s) + logw - C0;
    }
    __syncthreads();

    // Emit the 12 B-fragments (768 lane-slots of 8 bf16 = 16 B each).
    for (int idx = t; idx < 4 * 3 * 64; idx += 256) {
        const int ct = idx / 192;          // col-tile 0..3
        const int kt = (idx / 64) % 3;     // k-tile 0..2
        const int ln = idx & 63;
        const int col = ct * 16 + (ln & 15);
        const int kb = (ln >> 4) * 8;
        short8 v;
        if (kt < 2) {
#pragma unroll
            for (int e = 0; e < 8; ++e)
                v[e] = (short)f2bf(Ls[col][kt * 32 + kb + e]);
        } else {
#pragma unroll
            for (int e = 0; e < 8; ++e)
                v[e] = (short)((kb + e == 0) ? f2bf(-qs[col]) : 0);
        }
        *(short8*)(Bpack + ((size_t)(k * 12 + ct * 3 + kt) * 64 + ln) * 8) = v;
    }
}

// ============================================================================
// Main: wave = (row-tile of 16, k-subset of 4). 16384 waves, 4096 blocks.
// Per k: 12 MFMAs (4 col-tiles x [j0-31, j32-63, augmented -q tile]) give
// y - q directly in C-layout; maha via in-lane squares + 16-lane butterfly;
// exp(logp - C0) accumulated as a plain sum (fixed-max logsumexp).
// ============================================================================
__global__ __launch_bounds__(256, 4) void main_kernel(
    const float* __restrict__ X, const short* __restrict__ Bpack,
    const float* __restrict__ cstC, float* __restrict__ partials)
{
    const int tid = threadIdx.x;
    const int lane = tid & 63;
    const int wv = tid >> 6;
    const int w = blockIdx.x * 4 + wv;
    const int rt = w >> 3;                 // 0..2047
    const int ks = w & 7;                  // 0..7

    // A fragments from X (bf16 RNE): A[m=lane&15][k=(lane>>4)*8+e]
    const int row = rt * 16 + (lane & 15);
    const int jb = (lane >> 4) * 8;
    const float* Xr = X + row * DIM;
    short8 a0, a1;
#pragma unroll
    for (int e = 0; e < 8; ++e) {
        a0[e] = (short)f2bf(Xr[jb + e]);
        a1[e] = (short)f2bf(Xr[32 + jb + e]);
    }
    short8 a2 = (short8)0;                 // augmented tile: x_ext[64] = 1.0
    if (lane < 16) a2[0] = (short)0x3F80;  // k_local==0 lives in lanes 0..15,e=0

    const short8* Bp = (const short8*)Bpack;
    float acc = 0.f;
#pragma unroll
    for (int kk = 0; kk < 4; ++kk) {
        const int k = ks * 4 + kk;
        const short8* bk = Bp + (size_t)k * 12 * 64;
        float p0 = 0.f, p1 = 0.f, p2 = 0.f, p3 = 0.f;
#pragma unroll
        for (int ct = 0; ct < 4; ++ct) {
            short8 b0 = bk[(ct * 3 + 0) * 64 + lane];
            short8 b1 = bk[(ct * 3 + 1) * 64 + lane];
            short8 b2 = bk[(ct * 3 + 2) * 64 + lane];
            float4v c = {0.f, 0.f, 0.f, 0.f};
            c = __builtin_amdgcn_mfma_f32_16x16x32_bf16(a0, b0, c, 0, 0, 0);
            c = __builtin_amdgcn_mfma_f32_16x16x32_bf16(a1, b1, c, 0, 0, 0);
            c = __builtin_amdgcn_mfma_f32_16x16x32_bf16(a2, b2, c, 0, 0, 0);
            p0 = fmaf(c[0], c[0], p0);     // c = y - q for row (lane>>4)*4+r
            p1 = fmaf(c[1], c[1], p1);
            p2 = fmaf(c[2], c[2], p2);
            p3 = fmaf(c[3], c[3], p3);
        }
        // sum over the 16 cols held across lanes of the same group
#pragma unroll
        for (int m = 1; m <= 8; m <<= 1) {
            p0 += __shfl_xor(p0, m, 64);
            p1 += __shfl_xor(p1, m, 64);
            p2 += __shfl_xor(p2, m, 64);
            p3 += __shfl_xor(p3, m, 64);
        }
        const float cc = cstC[k];          // cst_k - C0 (wave-uniform s_load)
        acc += __expf(fmaf(-0.5f, p0, cc));
        acc += __expf(fmaf(-0.5f, p1, cc));
        acc += __expf(fmaf(-0.5f, p2, cc));
        acc += __expf(fmaf(-0.5f, p3, cc));
    }
    // groups hold disjoint rows (in-group lanes are duplicates): combine groups
    acc += __shfl_xor(acc, 16, 64);
    acc += __shfl_xor(acc, 32, 64);

    __shared__ float pm[4];
    if (lane == 0) pm[wv] = acc;
    __syncthreads();
    if (tid == 0)
        partials[blockIdx.x] = (pm[0] + pm[1]) + (pm[2] + pm[3]);
}

// ============================================================================
// Final: sum 4096 partials -> out = -(C0 + log(S))
// ============================================================================
__global__ __launch_bounds__(256) void final_kernel(
    const float* __restrict__ partials, int n, float* __restrict__ out)
{
    const int tid = threadIdx.x;
    float s = 0.f;
    for (int i = tid; i < n; i += 256) s += partials[i];
#pragma unroll
    for (int m = 1; m <= 32; m <<= 1) s += __shfl_xor(s, m, 64);
    __shared__ float pm[4];
    if ((tid & 63) == 0) pm[tid >> 6] = s;
    __syncthreads();
    if (tid == 0) out[0] = -(C0 + logf((pm[0] + pm[1]) + (pm[2] + pm[3])));
}

extern "C" void kernel_launch(void* const* d_in, const int* in_sizes, int n_in,
                              void* d_out, int out_size, void* d_ws, size_t ws_size,
                              hipStream_t stream) {
    const float* X  = (const float*)d_in[0];   // [32768,64]
    const float* mu = (const float*)d_in[1];   // [32,64]
    const float* L  = (const float*)d_in[2];   // [32,64,64]
    const float* w  = (const float*)d_in[3];   // [32]
    // d_in[4] = it (unused)

    char* ws = (char*)d_ws;
    short* Bpack = (short*)ws;                         // 32*12*64*8 bf16 = 384 KB
    float* cstC  = (float*)(ws + 32 * 12 * 64 * 8 * 2);
    float* parts = cstC + KC;                          // 4096 floats

    prep_kernel<<<KC, 256, 0, stream>>>(L, mu, w, Bpack, cstC);
    main_kernel<<<4096, 256, 0, stream>>>(X, Bpack, cstC, parts);
    final_kernel<<<1, 256, 0, stream>>>(parts, 4096, (float*)d_out);
}